// Round 3
// baseline (44.937 us; speedup 1.0000x reference)
//
#include <hip/hip_runtime.h>

// Fused elastic wave time step (seistorch), B=4, NZ=NX=1024, f32.
// One block = one full x-row (256 threads x float4 = 1024 = NX), marching an
// R-row strip in z. Stress rows go into a 3-slot rolling LDS buffer (one
// barrier per row) and are consumed by the velocity update of the same row
// (which needs stress rows r and r-1) -> fresh stresses never re-read from
// global. Circular-roll wrap via &(N-1).

constexpr int Bn = 4, NZ = 1024, NX = 1024;
constexpr int PLANE = NZ * NX;
constexpr int NPTS = Bn * PLANE;
constexpr int R = 4;                 // rows per strip
constexpr int NSTRIP = NZ / R;       // 256
constexpr int LOG_NSTRIP = 8;

__global__ __launch_bounds__(256, 4) void fused_wave_kernel(
    const float* __restrict__ vp, const float* __restrict__ vs,
    const float* __restrict__ rho, const float* __restrict__ vx,
    const float* __restrict__ vz, const float* __restrict__ txx,
    const float* __restrict__ tzz, const float* __restrict__ txz,
    const float* __restrict__ dtp, const float* __restrict__ hp,
    const float* __restrict__ dpml,
    float* __restrict__ y_vx, float* __restrict__ y_vz,
    float* __restrict__ y_txx, float* __restrict__ y_tzz,
    float* __restrict__ y_txz)
{
    __shared__ float s_txx[3][NX];
    __shared__ float s_tzz[3][NX];
    __shared__ float s_txz[3][NX];

    const int tid = threadIdx.x;
    const int x0 = tid * 4;
    const int xm1 = (x0 - 1) & (NX - 1);
    const int xp4 = (x0 + 4) & (NX - 1);
    const int strip = blockIdx.x & (NSTRIP - 1);
    const int b = blockIdx.x >> LOG_NSTRIP;
    const int z0 = strip * R;
    const size_t fb = (size_t)b * PLANE;

    const float dt = dtp[0], h = hp[0];
    const float dth = dt / h;

    const int rm0 = (z0 - 1) & (NZ - 1);
    float4 vxr = *(const float4*)(vx + fb + (size_t)rm0 * NX + x0);
    float4 vzr = *(const float4*)(vz + fb + (size_t)rm0 * NX + x0);

    int slot = 0;                     // k % 3
    int pslot = 2;                    // (k-1) % 3

    for (int k = 0; k <= R; ++k) {
        const int r  = (z0 - 1 + k) & (NZ - 1);
        const int rp = (r + 1) & (NZ - 1);
        const size_t rowb  = fb + (size_t)r * NX;
        const size_t rowbp = fb + (size_t)rp * NX;
        const int mrow = r * NX;

        float4 vxr1 = *(const float4*)(vx + rowbp + x0);
        float4 vzr1 = *(const float4*)(vz + rowbp + x0);
        float  vxm  = vx[rowb + xm1];
        float  vzp  = vz[rowb + xp4];
        float4 txxo = *(const float4*)(txx + rowb + x0);
        float4 tzzo = *(const float4*)(tzz + rowb + x0);
        float4 txzo = *(const float4*)(txz + rowb + x0);
        float4 vpv  = *(const float4*)(vp + mrow + x0);
        float4 vsv  = *(const float4*)(vs + mrow + x0);
        float4 rhv  = *(const float4*)(rho + mrow + x0);
        float4 dv   = *(const float4*)(dpml + mrow + x0);

        float fvx[5]  = {vxm, vxr.x, vxr.y, vxr.z, vxr.w};
        float fvz[5]  = {vzr.x, vzr.y, vzr.z, vzr.w, vzp};
        float fvx1[4] = {vxr1.x, vxr1.y, vxr1.z, vxr1.w};
        float fvz1[4] = {vzr1.x, vzr1.y, vzr1.z, vzr1.w};
        float ftxxo[4] = {txxo.x, txxo.y, txxo.z, txxo.w};
        float ftzzo[4] = {tzzo.x, tzzo.y, tzzo.z, tzzo.w};
        float ftxzo[4] = {txzo.x, txzo.y, txzo.z, txzo.w};
        float fvp[4] = {vpv.x, vpv.y, vpv.z, vpv.w};
        float fvs[4] = {vsv.x, vsv.y, vsv.z, vsv.w};
        float frh[4] = {rhv.x, rhv.y, rhv.z, rhv.w};
        float fd[4]  = {dv.x, dv.y, dv.z, dv.w};

        float o_txx[4], o_tzz[4], o_txz[4], inv[4], omc[4];
#pragma unroll
        for (int i = 0; i < 4; ++i) {
            float lam = frh[i] * (fvp[i] * fvp[i] - 2.0f * fvs[i] * fvs[i]);
            float mu  = frh[i] * fvs[i] * fvs[i];
            float vx_x = fvx[i + 1] - fvx[i];     // vx[x] - vx[x-1]
            float vz_z = fvz1[i] - fvz[i];        // vz[z+1] - vz[z]
            float vx_z = fvx1[i] - fvx[i + 1];    // vx[z+1] - vx[z]
            float vz_x = fvz[i + 1] - fvz[i];     // vz[x+1] - vz[x]
            float c = 0.5f * dt * fd[i];
            inv[i] = 1.0f / (1.0f + c);
            omc[i] = 1.0f - c;
            float lp2m = lam + 2.0f * mu;
            o_txx[i] = inv[i] * (dth * (lp2m * vx_x + lam * vz_z) + omc[i] * ftxxo[i]);
            o_tzz[i] = inv[i] * (dth * (lp2m * vz_z + lam * vx_x) + omc[i] * ftzzo[i]);
            o_txz[i] = inv[i] * (dth * mu * (vz_x + vx_z) + omc[i] * ftxzo[i]);
        }

        *(float4*)&s_txx[slot][x0] = make_float4(o_txx[0], o_txx[1], o_txx[2], o_txx[3]);
        *(float4*)&s_tzz[slot][x0] = make_float4(o_tzz[0], o_tzz[1], o_tzz[2], o_tzz[3]);
        *(float4*)&s_txz[slot][x0] = make_float4(o_txz[0], o_txz[1], o_txz[2], o_txz[3]);
        if (k > 0) {
            *(float4*)(y_txx + rowb + x0) = make_float4(o_txx[0], o_txx[1], o_txx[2], o_txx[3]);
            *(float4*)(y_tzz + rowb + x0) = make_float4(o_tzz[0], o_tzz[1], o_tzz[2], o_tzz[3]);
            *(float4*)(y_txz + rowb + x0) = make_float4(o_txz[0], o_txz[1], o_txz[2], o_txz[3]);
        }
        __syncthreads();   // single barrier: slot now readable; max skew 1 iter

        if (k > 0) {
            float  txxp4v = s_txx[slot][xp4];
            float  txzm1v = s_txz[slot][xm1];
            float4 txzzm = *(const float4*)&s_txz[pslot][x0];
            float4 tzzzm = *(const float4*)&s_tzz[pslot][x0];

            float ftxx5[5] = {o_txx[0], o_txx[1], o_txx[2], o_txx[3], txxp4v};
            float ftxz5[5] = {txzm1v, o_txz[0], o_txz[1], o_txz[2], o_txz[3]};
            float ftxzzm[4] = {txzzm.x, txzzm.y, txzzm.z, txzzm.w};
            float ftzzzm[4] = {tzzzm.x, tzzzm.y, tzzzm.z, tzzzm.w};
            float fvxc[4] = {vxr.x, vxr.y, vxr.z, vxr.w};
            float fvzc[4] = {vzr.x, vzr.y, vzr.z, vzr.w};

            float o_vx[4], o_vz[4];
#pragma unroll
            for (int i = 0; i < 4; ++i) {
                float txx_x = ftxx5[i + 1] - ftxx5[i];   // txx[x+1]-txx[x]
                float txz_z = ftxz5[i + 1] - ftxzzm[i];  // txz[z]-txz[z-1]
                float tzz_z = o_tzz[i] - ftzzzm[i];      // tzz[z]-tzz[z-1]
                float txz_x = ftxz5[i + 1] - ftxz5[i];   // txz[x]-txz[x-1]
                float s = dth / frh[i];
                o_vx[i] = inv[i] * (s * (txx_x + txz_z) + omc[i] * fvxc[i]);
                o_vz[i] = inv[i] * (s * (txz_x + tzz_z) + omc[i] * fvzc[i]);
            }
            *(float4*)(y_vx + rowb + x0) = make_float4(o_vx[0], o_vx[1], o_vx[2], o_vx[3]);
            *(float4*)(y_vz + rowb + x0) = make_float4(o_vz[0], o_vz[1], o_vz[2], o_vz[3]);
        }

        vxr = vxr1;
        vzr = vzr1;
        pslot = slot;
        slot = (slot == 2) ? 0 : slot + 1;
    }
}

extern "C" void kernel_launch(void* const* d_in, const int* in_sizes, int n_in,
                              void* d_out, int out_size, void* d_ws, size_t ws_size,
                              hipStream_t stream) {
    const float* vp  = (const float*)d_in[0];
    const float* vs  = (const float*)d_in[1];
    const float* rho = (const float*)d_in[2];
    const float* vx  = (const float*)d_in[3];
    const float* vz  = (const float*)d_in[4];
    const float* txx = (const float*)d_in[5];
    const float* tzz = (const float*)d_in[6];
    const float* txz = (const float*)d_in[7];
    const float* dtp = (const float*)d_in[8];
    const float* hp  = (const float*)d_in[9];
    const float* dpm = (const float*)d_in[10];

    float* out   = (float*)d_out;
    float* y_vx  = out;
    float* y_vz  = out + (size_t)NPTS;
    float* y_txx = out + 2 * (size_t)NPTS;
    float* y_tzz = out + 3 * (size_t)NPTS;
    float* y_txz = out + 4 * (size_t)NPTS;

    dim3 block(256);
    dim3 grid(Bn * NSTRIP);   // 1024 blocks, 4 per CU
    fused_wave_kernel<<<grid, block, 0, stream>>>(vp, vs, rho, vx, vz, txx, tzz, txz,
                                                  dtp, hp, dpm,
                                                  y_vx, y_vz, y_txx, y_tzz, y_txz);
}

// Round 4
// 37.185 us; speedup vs baseline: 1.2085x; 1.2085x over previous
//
#include <hip/hip_runtime.h>

// Fused elastic wave time step (seistorch), B=4, NZ=NX=1024, f32.
// One block = one full x-row (256 threads x float4 = 1024 = NX), marching an
// R=8 row strip in z. Stress rows go into a 3-slot rolling LDS buffer with a
// single raw s_barrier per row (lgkmcnt-only drain, so prefetched global
// loads stay in flight across the barrier). Depth-1 software pipeline: all
// global loads for iteration k+1 issue before iteration k's compute.
// Circular-roll wrap via &(N-1).

constexpr int Bn = 4, NZ = 1024, NX = 1024;
constexpr int PLANE = NZ * NX;
constexpr int NPTS = Bn * PLANE;
constexpr int R = 8;                 // rows per strip
constexpr int NSTRIP = NZ / R;       // 128
constexpr int LOG_NSTRIP = 7;

__global__ __launch_bounds__(256, 2) void fused_wave_kernel(
    const float* __restrict__ vp, const float* __restrict__ vs,
    const float* __restrict__ rho, const float* __restrict__ vx,
    const float* __restrict__ vz, const float* __restrict__ txx,
    const float* __restrict__ tzz, const float* __restrict__ txz,
    const float* __restrict__ dtp, const float* __restrict__ hp,
    const float* __restrict__ dpml,
    float* __restrict__ y_vx, float* __restrict__ y_vz,
    float* __restrict__ y_txx, float* __restrict__ y_tzz,
    float* __restrict__ y_txz)
{
    __shared__ float s_txx[3][NX];
    __shared__ float s_tzz[3][NX];
    __shared__ float s_txz[3][NX];

    const int tid = threadIdx.x;
    const int x0 = tid * 4;
    const int xm1 = (x0 - 1) & (NX - 1);
    const int xp4 = (x0 + 4) & (NX - 1);
    const int strip = blockIdx.x & (NSTRIP - 1);
    const int b = blockIdx.x >> LOG_NSTRIP;
    const int z0 = strip * R;
    const size_t fb = (size_t)b * PLANE;

    const float dt = dtp[0], h = hp[0];
    const float dth = dt / h;

    // ---- prologue: loads for iteration k=0 (row z0-1) + vx/vz row z0 ----
    const int r0 = (z0 - 1) & (NZ - 1);
    const int r1 = z0;
    const size_t rb0 = fb + (size_t)r0 * NX;
    const size_t rb1 = fb + (size_t)r1 * NX;
    const int m0 = r0 * NX;

    float4 cvx = *(const float4*)(vx + rb0 + x0);
    float4 cvz = *(const float4*)(vz + rb0 + x0);
    float4 nvx = *(const float4*)(vx + rb1 + x0);
    float4 nvz = *(const float4*)(vz + rb1 + x0);
    float  cvxm = vx[rb0 + xm1];
    float  cvzp = vz[rb0 + xp4];
    float4 ctxx = *(const float4*)(txx + rb0 + x0);
    float4 ctzz = *(const float4*)(tzz + rb0 + x0);
    float4 ctxz = *(const float4*)(txz + rb0 + x0);
    float4 cvp = *(const float4*)(vp + m0 + x0);
    float4 cvs = *(const float4*)(vs + m0 + x0);
    float4 crh = *(const float4*)(rho + m0 + x0);
    float4 cd  = *(const float4*)(dpml + m0 + x0);

#pragma unroll
    for (int k = 0; k <= R; ++k) {
        const int r = (z0 - 1 + k) & (NZ - 1);
        const size_t rowb = fb + (size_t)r * NX;

        // ---- prefetch everything for iteration k+1 (row r+1) ----
        float4 n2vx, n2vz, ntxx, ntzz, ntxz, nvp, nvs, nrh, nd;
        float  nvxm = 0.f, nvzp = 0.f;
        if (k < R) {
            const int rn  = (z0 + k) & (NZ - 1);        // row r+1
            const int rn2 = (z0 + k + 1) & (NZ - 1);    // row r+2
            const size_t rbn  = fb + (size_t)rn * NX;
            const size_t rbn2 = fb + (size_t)rn2 * NX;
            const int mn = rn * NX;
            n2vx = *(const float4*)(vx + rbn2 + x0);
            n2vz = *(const float4*)(vz + rbn2 + x0);
            nvxm = vx[rbn + xm1];
            nvzp = vz[rbn + xp4];
            ntxx = *(const float4*)(txx + rbn + x0);
            ntzz = *(const float4*)(tzz + rbn + x0);
            ntxz = *(const float4*)(txz + rbn + x0);
            nvp = *(const float4*)(vp + mn + x0);
            nvs = *(const float4*)(vs + mn + x0);
            nrh = *(const float4*)(rho + mn + x0);
            nd  = *(const float4*)(dpml + mn + x0);
        }

        // ---- stress row r from current registers ----
        float fvx[5]  = {cvxm, cvx.x, cvx.y, cvx.z, cvx.w};
        float fvz[5]  = {cvz.x, cvz.y, cvz.z, cvz.w, cvzp};
        float fvx1[4] = {nvx.x, nvx.y, nvx.z, nvx.w};
        float fvz1[4] = {nvz.x, nvz.y, nvz.z, nvz.w};
        float ftxxo[4] = {ctxx.x, ctxx.y, ctxx.z, ctxx.w};
        float ftzzo[4] = {ctzz.x, ctzz.y, ctzz.z, ctzz.w};
        float ftxzo[4] = {ctxz.x, ctxz.y, ctxz.z, ctxz.w};
        float fvp[4] = {cvp.x, cvp.y, cvp.z, cvp.w};
        float fvs[4] = {cvs.x, cvs.y, cvs.z, cvs.w};
        float frh[4] = {crh.x, crh.y, crh.z, crh.w};
        float fd[4]  = {cd.x, cd.y, cd.z, cd.w};

        float o_txx[4], o_tzz[4], o_txz[4], inv[4], omc[4];
#pragma unroll
        for (int i = 0; i < 4; ++i) {
            float lam = frh[i] * (fvp[i] * fvp[i] - 2.0f * fvs[i] * fvs[i]);
            float mu  = frh[i] * fvs[i] * fvs[i];
            float vx_x = fvx[i + 1] - fvx[i];     // vx[x] - vx[x-1]
            float vz_z = fvz1[i] - fvz[i];        // vz[z+1] - vz[z]
            float vx_z = fvx1[i] - fvx[i + 1];    // vx[z+1] - vx[z]
            float vz_x = fvz[i + 1] - fvz[i];     // vz[x+1] - vz[x]
            float c = 0.5f * dt * fd[i];
            inv[i] = 1.0f / (1.0f + c);
            omc[i] = 1.0f - c;
            float lp2m = lam + 2.0f * mu;
            o_txx[i] = inv[i] * (dth * (lp2m * vx_x + lam * vz_z) + omc[i] * ftxxo[i]);
            o_tzz[i] = inv[i] * (dth * (lp2m * vz_z + lam * vx_x) + omc[i] * ftzzo[i]);
            o_txz[i] = inv[i] * (dth * mu * (vz_x + vx_z) + omc[i] * ftxzo[i]);
        }

        const int slot = k % 3;            // compile-time (loop unrolled)
        const int pslot = (k + 2) % 3;     // (k-1) % 3
        *(float4*)&s_txx[slot][x0] = make_float4(o_txx[0], o_txx[1], o_txx[2], o_txx[3]);
        *(float4*)&s_tzz[slot][x0] = make_float4(o_tzz[0], o_tzz[1], o_tzz[2], o_tzz[3]);
        *(float4*)&s_txz[slot][x0] = make_float4(o_txz[0], o_txz[1], o_txz[2], o_txz[3]);
        if (k > 0) {
            *(float4*)(y_txx + rowb + x0) = make_float4(o_txx[0], o_txx[1], o_txx[2], o_txx[3]);
            *(float4*)(y_tzz + rowb + x0) = make_float4(o_tzz[0], o_tzz[1], o_tzz[2], o_tzz[3]);
            *(float4*)(y_txz + rowb + x0) = make_float4(o_txz[0], o_txz[1], o_txz[2], o_txz[3]);
        }

        // LDS-only drain + raw barrier: prefetched global loads stay in
        // flight (no vmcnt(0) drain as __syncthreads would emit).
        asm volatile("s_waitcnt lgkmcnt(0)" ::: "memory");
        __builtin_amdgcn_s_barrier();

        if (k > 0) {
            float  txxp4v = s_txx[slot][xp4];
            float  txzm1v = s_txz[slot][xm1];
            float4 txzzm = *(const float4*)&s_txz[pslot][x0];
            float4 tzzzm = *(const float4*)&s_tzz[pslot][x0];

            float ftxx5[5] = {o_txx[0], o_txx[1], o_txx[2], o_txx[3], txxp4v};
            float ftxz5[5] = {txzm1v, o_txz[0], o_txz[1], o_txz[2], o_txz[3]};
            float ftxzzm[4] = {txzzm.x, txzzm.y, txzzm.z, txzzm.w};
            float ftzzzm[4] = {tzzzm.x, tzzzm.y, tzzzm.z, tzzzm.w};
            float fvxc[4] = {cvx.x, cvx.y, cvx.z, cvx.w};
            float fvzc[4] = {cvz.x, cvz.y, cvz.z, cvz.w};

            float o_vx[4], o_vz[4];
#pragma unroll
            for (int i = 0; i < 4; ++i) {
                float txx_x = ftxx5[i + 1] - ftxx5[i];   // txx[x+1]-txx[x]
                float txz_z = ftxz5[i + 1] - ftxzzm[i];  // txz[z]-txz[z-1]
                float tzz_z = o_tzz[i] - ftzzzm[i];      // tzz[z]-tzz[z-1]
                float txz_x = ftxz5[i + 1] - ftxz5[i];   // txz[x]-txz[x-1]
                float s = dth / frh[i];
                o_vx[i] = inv[i] * (s * (txx_x + txz_z) + omc[i] * fvxc[i]);
                o_vz[i] = inv[i] * (s * (txz_x + tzz_z) + omc[i] * fvzc[i]);
            }
            *(float4*)(y_vx + rowb + x0) = make_float4(o_vx[0], o_vx[1], o_vx[2], o_vx[3]);
            *(float4*)(y_vz + rowb + x0) = make_float4(o_vz[0], o_vz[1], o_vz[2], o_vz[3]);
        }

        // ---- rotate pipeline registers ----
        cvx = nvx; cvz = nvz;
        nvx = n2vx; nvz = n2vz;
        cvxm = nvxm; cvzp = nvzp;
        ctxx = ntxx; ctzz = ntzz; ctxz = ntxz;
        cvp = nvp; cvs = nvs; crh = nrh; cd = nd;
    }
}

extern "C" void kernel_launch(void* const* d_in, const int* in_sizes, int n_in,
                              void* d_out, int out_size, void* d_ws, size_t ws_size,
                              hipStream_t stream) {
    const float* vp  = (const float*)d_in[0];
    const float* vs  = (const float*)d_in[1];
    const float* rho = (const float*)d_in[2];
    const float* vx  = (const float*)d_in[3];
    const float* vz  = (const float*)d_in[4];
    const float* txx = (const float*)d_in[5];
    const float* tzz = (const float*)d_in[6];
    const float* txz = (const float*)d_in[7];
    const float* dtp = (const float*)d_in[8];
    const float* hp  = (const float*)d_in[9];
    const float* dpm = (const float*)d_in[10];

    float* out   = (float*)d_out;
    float* y_vx  = out;
    float* y_vz  = out + (size_t)NPTS;
    float* y_txx = out + 2 * (size_t)NPTS;
    float* y_tzz = out + 3 * (size_t)NPTS;
    float* y_txz = out + 4 * (size_t)NPTS;

    dim3 block(256);
    dim3 grid(Bn * NSTRIP);   // 512 blocks, 2 per CU
    fused_wave_kernel<<<grid, block, 0, stream>>>(vp, vs, rho, vx, vz, txx, tzz, txz,
                                                  dtp, hp, dpm,
                                                  y_vx, y_vz, y_txx, y_tzz, y_txz);
}